// Round 1
// baseline (6549.740 us; speedup 1.0000x reference)
//
#include <hip/hip_runtime.h>

typedef _Float16 half_t;
typedef _Float16 half8  __attribute__((ext_vector_type(8)));
typedef _Float16 half4v __attribute__((ext_vector_type(4)));
typedef float    f32x4  __attribute__((ext_vector_type(4)));

#define NB 64
#define NT 256
#define NI 1024
#define NH 512

// ---------------- group barrier (device-scope, monotonic counter) ----------------
__device__ __forceinline__ void grp_barrier(unsigned* c, unsigned per, unsigned gen) {
    __syncthreads();                       // all WG threads done; vmcnt/lgkmcnt drained
    if (threadIdx.x == 0) {
        __builtin_amdgcn_fence(__ATOMIC_RELEASE, "agent");
        __hip_atomic_fetch_add(c, 1u, __ATOMIC_RELAXED, __HIP_MEMORY_SCOPE_AGENT);
        const unsigned target = per * gen;
        long guard = 0;
        while (__hip_atomic_load(c, __ATOMIC_RELAXED, __HIP_MEMORY_SCOPE_AGENT) < target) {
            __builtin_amdgcn_s_sleep(2);
            if (++guard > (1LL << 31)) break;  // failsafe: wrong answer beats a hang
        }
        __builtin_amdgcn_fence(__ATOMIC_ACQUIRE, "agent");
    }
    __syncthreads();
}

// ---------------- fp32 -> fp16 convert ----------------
__global__ __launch_bounds__(256) void k_cvt(const float* __restrict__ s,
                                             half_t* __restrict__ d, int n4) {
    int i = blockIdx.x * 256 + threadIdx.x;
    if (i < n4) {
        float4 v = reinterpret_cast<const float4*>(s)[i];
        half4v h;
        h[0] = (half_t)v.x; h[1] = (half_t)v.y; h[2] = (half_t)v.z; h[3] = (half_t)v.w;
        reinterpret_cast<half4v*>(d)[i] = h;
    }
}

// ---------------- GEMM: C[M,N](f16) = A[M,K](f16) * Bw[N,K]^T + bias ----------------
// 128x128 tile, BK=64, 4 waves (2x2 quadrants of 64x64), double-buffered LDS,
// XOR chunk-swizzle (chunk ^= row&7) so ds_read_b128 fragment reads are conflict-free.
template <int K>
__global__ __launch_bounds__(256) void k_gemm(const half_t* __restrict__ A,
                                              const half_t* __restrict__ Bw,
                                              const float* __restrict__ bias,
                                              half_t* __restrict__ C, int N) {
    constexpr int BK = 64;
    __shared__ half_t Al[2][128 * BK] __attribute__((aligned(16)));
    __shared__ half_t Bl[2][128 * BK] __attribute__((aligned(16)));

    const int tid = threadIdx.x, lane = tid & 63, wv = tid >> 6;
    const long m0 = (long)blockIdx.y * 128;
    const long n0 = (long)blockIdx.x * 128;
    const int wm = (wv >> 1) * 64, wn = (wv & 1) * 64;

    f32x4 acc[4][4];
#pragma unroll
    for (int nt = 0; nt < 4; ++nt) {
        float bv = bias[n0 + wn + nt * 16 + (lane & 15)];
#pragma unroll
        for (int mt = 0; mt < 4; ++mt) acc[mt][nt] = (f32x4){bv, bv, bv, bv};
    }

    auto stage = [&](int buf, int kt) {
#pragma unroll
        for (int j = 0; j < 4; ++j) {
            int c = tid + 256 * j;             // 1024 16B-chunks per tile
            int row = c >> 3, cin = c & 7;
            int dst = row * BK + ((cin ^ (row & 7)) << 3);
            *reinterpret_cast<int4*>(&Al[buf][dst]) =
                *reinterpret_cast<const int4*>(A + (m0 + row) * K + kt * BK + cin * 8);
            *reinterpret_cast<int4*>(&Bl[buf][dst]) =
                *reinterpret_cast<const int4*>(Bw + (n0 + row) * K + kt * BK + cin * 8);
        }
    };

    stage(0, 0);
    __syncthreads();
    constexpr int NK = K / BK;
    int buf = 0;
    for (int kt = 0; kt < NK; ++kt) {
        if (kt + 1 < NK) stage(buf ^ 1, kt + 1);
        half8 af[4][2], bf[4][2];
#pragma unroll
        for (int mt = 0; mt < 4; ++mt)
#pragma unroll
            for (int ks = 0; ks < 2; ++ks) {
                int lr = wm + mt * 16 + (lane & 15);
                int off = lr * BK + ((ks * 32 + 8 * (lane >> 4)) ^ ((lr & 7) << 3));
                af[mt][ks] = *reinterpret_cast<const half8*>(&Al[buf][off]);
            }
#pragma unroll
        for (int nt = 0; nt < 4; ++nt)
#pragma unroll
            for (int ks = 0; ks < 2; ++ks) {
                int lr = wn + nt * 16 + (lane & 15);
                int off = lr * BK + ((ks * 32 + 8 * (lane >> 4)) ^ ((lr & 7) << 3));
                bf[nt][ks] = *reinterpret_cast<const half8*>(&Bl[buf][off]);
            }
#pragma unroll
        for (int mt = 0; mt < 4; ++mt)
#pragma unroll
            for (int nt = 0; nt < 4; ++nt)
#pragma unroll
                for (int ks = 0; ks < 2; ++ks)
                    acc[mt][nt] = __builtin_amdgcn_mfma_f32_16x16x32_f16(
                        af[mt][ks], bf[nt][ks], acc[mt][nt], 0, 0, 0);
        __syncthreads();
        buf ^= 1;
    }
#pragma unroll
    for (int mt = 0; mt < 4; ++mt)
#pragma unroll
        for (int nt = 0; nt < 4; ++nt)
#pragma unroll
            for (int i = 0; i < 4; ++i) {
                long row = m0 + wm + mt * 16 + 4 * (lane >> 4) + i;
                long col = n0 + wn + nt * 16 + (lane & 15);
                C[row * N + col] = (half_t)acc[mt][nt][i];
            }
}

// ---------------- Phase 1: layer-1 recurrence (persistent) ----------------
// 8 groups (XCD-affine via bid&7) x 32 WGs. Group g owns batches [8g,8g+8).
// WG owns 16 h-elems: gate rows {e, 512+e, 1024+e}. Weights resident in LDS.
__global__ __launch_bounds__(256, 1) void k_phase1(const half_t* __restrict__ whh,
                                                   const float* __restrict__ bhh,
                                                   const half_t* __restrict__ gx,
                                                   half_t* __restrict__ hrelu,
                                                   half_t* __restrict__ hf16,
                                                   float* __restrict__ hf32,
                                                   unsigned* __restrict__ ctr) {
    __shared__ half_t wl[48 * NH] __attribute__((aligned(16)));   // 48KB
    __shared__ half_t hl[16 * NH] __attribute__((aligned(16)));   // 16KB
    __shared__ float xch[3][8][16];

    const int tid = threadIdx.x, lane = tid & 63, wv = tid >> 6;
    const int g = blockIdx.x & 7, memb = blockIdx.x >> 3;
    const int e0 = memb * 16;

    // resident weight slice: local row lr = 16*gate + e  ->  global row gate*512+e0+e
#pragma unroll
    for (int j = 0; j < 12; ++j) {
        int c = tid + 256 * j;                 // 3072 chunks
        int lr = c >> 6, cin = c & 63;
        int grow = (lr >> 4) * NH + e0 + (lr & 15);
        int dst = lr * NH + ((cin ^ (lr & 7)) << 3);
        *reinterpret_cast<int4*>(&wl[dst]) =
            *reinterpret_cast<const int4*>(whh + (long)grow * NH + cin * 8);
    }
    // zero A-tile pad rows 8..15 (stay zero forever)
#pragma unroll
    for (int j = 0; j < 2; ++j) {
        int c = tid + 256 * j;                 // 512 chunks
        int lr = 8 + (c >> 6), cin = c & 63;
        int4 z; z.x = z.y = z.z = z.w = 0;
        *reinterpret_cast<int4*>(&hl[lr * NH + cin * 8]) = z;
    }
    // zero h state (buffer 0 + fp32) for this WG's (batch, elem) slice
    if (tid < 128) {
        int b = tid >> 4, e = tid & 15;
        int idx = (g * 8 + b) * NH + e0 + e;
        hf16[idx] = (half_t)0.f;
        hf32[idx] = 0.f;
    }
    grp_barrier(ctr + g, 32, 1);

    const float bgate = (wv < 3) ? bhh[wv * NH + e0 + (lane & 15)] : 0.f;

    for (int t = 0; t < NT; ++t) {
        // stage current h (8 rows x 512) into swizzled LDS
        const half_t* hsrc = hf16 + (t & 1) * (NB * NH);
#pragma unroll
        for (int j = 0; j < 2; ++j) {
            int c = tid + 256 * j;             // 512 chunks
            int lr = c >> 6, cin = c & 63;
            *reinterpret_cast<int4*>(&hl[lr * NH + ((cin ^ (lr & 7)) << 3)]) =
                *reinterpret_cast<const int4*>(hsrc + (g * 8 + lr) * NH + cin * 8);
        }
        __syncthreads();

        if (wv < 3) {                          // wave wv computes gate wv
            f32x4 acc = (f32x4){bgate, bgate, bgate, bgate};
#pragma unroll
            for (int ks = 0; ks < 16; ++ks) {
                int ar = lane & 15;
                int ao = ar * NH + ((ks * 32 + 8 * (lane >> 4)) ^ ((ar & 7) << 3));
                half8 a = *reinterpret_cast<const half8*>(&hl[ao]);
                int br = wv * 16 + (lane & 15);
                int bo = br * NH + ((ks * 32 + 8 * (lane >> 4)) ^ ((br & 7) << 3));
                half8 b = *reinterpret_cast<const half8*>(&wl[bo]);
                acc = __builtin_amdgcn_mfma_f32_16x16x32_f16(a, b, acc, 0, 0, 0);
            }
            if (lane < 32) {                   // batches 0..7 live in lanes 0..31
#pragma unroll
                for (int i = 0; i < 4; ++i)
                    xch[wv][4 * (lane >> 4) + i][lane & 15] = acc[i];
            }
        }
        __syncthreads();

        if (tid < 128) {                       // gate combine: one thread per (b,e)
            int b = tid >> 4, e = tid & 15;
            long rowbase = (long)(g * 8 + b) * NT + t;
            long gbase = rowbase * (3 * NH) + e0 + e;
            float xr = (float)gx[gbase];
            float xz = (float)gx[gbase + NH];
            float xn = (float)gx[gbase + 2 * NH];
            int sidx = (g * 8 + b) * NH + e0 + e;
            float hp = hf32[sidx];
            float r = 1.f / (1.f + __expf(-(xr + xch[0][b][e])));
            float z = 1.f / (1.f + __expf(-(xz + xch[1][b][e])));
            float n = tanhf(xn + r * xch[2][b][e]);
            float hn = (1.f - z) * n + z * hp;
            hf32[sidx] = hn;
            hf16[((t + 1) & 1) * (NB * NH) + sidx] = (half_t)hn;
            hrelu[rowbase * NH + e0 + e] = (half_t)fmaxf(hn, 0.f);
        }
        grp_barrier(ctr + g, 32, t + 2);
    }
}

// ---------------- Phase 2: layer-2 recurrence (persistent) ----------------
// 4 groups (XCD pairs) x 64 WGs. Group g owns batches [16g,16g+16).
// WG owns 16 out-elems: gate rows {e, 1024+e, 2048+e}; 96KB weights in LDS.
__global__ __launch_bounds__(256, 1) void k_phase2(const half_t* __restrict__ whh,
                                                   const float* __restrict__ bhh,
                                                   const half_t* __restrict__ gx,
                                                   float* __restrict__ out,
                                                   half_t* __restrict__ hf16,
                                                   float* __restrict__ hf32,
                                                   unsigned* __restrict__ ctr) {
    __shared__ half_t wl[48 * NI] __attribute__((aligned(16)));   // 96KB
    __shared__ half_t hl[16 * NI] __attribute__((aligned(16)));   // 32KB
    __shared__ float xch[3][16][16];

    const int tid = threadIdx.x, lane = tid & 63, wv = tid >> 6;
    const int xcd = blockIdx.x & 7;
    const int g = xcd >> 1;
    const int memb = ((blockIdx.x >> 3) << 1) | (xcd & 1);  // 0..63
    const int e0 = memb * 16;

#pragma unroll
    for (int j = 0; j < 24; ++j) {
        int c = tid + 256 * j;                 // 6144 chunks
        int lr = c >> 7, cin = c & 127;
        int grow = (lr >> 4) * NI + e0 + (lr & 15);
        int dst = lr * NI + ((cin ^ (lr & 7)) << 3);
        *reinterpret_cast<int4*>(&wl[dst]) =
            *reinterpret_cast<const int4*>(whh + (long)grow * NI + cin * 8);
    }
    {
        int b = tid >> 4, e = tid & 15;
        int idx = (g * 16 + b) * NI + e0 + e;
        hf16[idx] = (half_t)0.f;
        hf32[idx] = 0.f;
    }
    grp_barrier(ctr + g, 64, 1);

    const float bgate = (wv < 3) ? bhh[wv * NI + e0 + (lane & 15)] : 0.f;

    for (int t = 0; t < NT; ++t) {
        const half_t* hsrc = hf16 + (t & 1) * (NB * NI);
#pragma unroll
        for (int j = 0; j < 8; ++j) {
            int c = tid + 256 * j;             // 2048 chunks
            int lr = c >> 7, cin = c & 127;
            *reinterpret_cast<int4*>(&hl[lr * NI + ((cin ^ (lr & 7)) << 3)]) =
                *reinterpret_cast<const int4*>(hsrc + (g * 16 + lr) * NI + cin * 8);
        }
        __syncthreads();

        if (wv < 3) {
            f32x4 acc = (f32x4){bgate, bgate, bgate, bgate};
#pragma unroll
            for (int ks = 0; ks < 32; ++ks) {
                int ar = lane & 15;
                int ao = ar * NI + ((ks * 32 + 8 * (lane >> 4)) ^ ((ar & 7) << 3));
                half8 a = *reinterpret_cast<const half8*>(&hl[ao]);
                int br = wv * 16 + (lane & 15);
                int bo = br * NI + ((ks * 32 + 8 * (lane >> 4)) ^ ((br & 7) << 3));
                half8 b = *reinterpret_cast<const half8*>(&wl[bo]);
                acc = __builtin_amdgcn_mfma_f32_16x16x32_f16(a, b, acc, 0, 0, 0);
            }
#pragma unroll
            for (int i = 0; i < 4; ++i)
                xch[wv][4 * (lane >> 4) + i][lane & 15] = acc[i];
        }
        __syncthreads();

        {
            int b = tid >> 4, e = tid & 15;
            long rowbase = (long)(g * 16 + b) * NT + t;
            long gbase = rowbase * (3 * NI) + e0 + e;
            float xr = (float)gx[gbase];
            float xz = (float)gx[gbase + NI];
            float xn = (float)gx[gbase + 2 * NI];
            int sidx = (g * 16 + b) * NI + e0 + e;
            float hp = hf32[sidx];
            float r = 1.f / (1.f + __expf(-(xr + xch[0][b][e])));
            float z = 1.f / (1.f + __expf(-(xz + xch[1][b][e])));
            float n = tanhf(xn + r * xch[2][b][e]);
            float hn = (1.f - z) * n + z * hp;
            hf32[sidx] = hn;
            hf16[((t + 1) & 1) * (NB * NI) + sidx] = (half_t)hn;
            out[rowbase * NI + e0 + e] = hn;
        }
        grp_barrier(ctr + g, 64, t + 2);
    }
}

// ---------------- launcher ----------------
extern "C" void kernel_launch(void* const* d_in, const int* in_sizes, int n_in,
                              void* d_out, int out_size, void* d_ws, size_t ws_size,
                              hipStream_t stream) {
    const float* x     = (const float*)d_in[0];
    const float* w_ih1 = (const float*)d_in[1];
    const float* w_hh1 = (const float*)d_in[2];
    const float* b_ih1 = (const float*)d_in[3];
    const float* b_hh1 = (const float*)d_in[4];
    const float* w_ih2 = (const float*)d_in[5];
    const float* w_hh2 = (const float*)d_in[6];
    const float* b_ih2 = (const float*)d_in[7];
    const float* b_hh2 = (const float*)d_in[8];

    char* ws = (char*)d_ws;
    // ws layout (total ~144MB):
    unsigned* ctr  = (unsigned*)ws;                    // [0, 4K): barrier counters
    half_t* h1f16  = (half_t*)(ws + 4096);             // 2 x 64x512 fp16 ping-pong
    float*  h1f32  = (float*) (ws + 135168);           // 64x512 fp32 state
    half_t* h2f16  = (half_t*)(ws + 266240);           // 2 x 64x1024 fp16
    float*  h2f32  = (float*) (ws + 528384);           // 64x1024 fp32
    half_t* wih1h  = (half_t*)(ws + 1048576);          // 1536x1024
    half_t* whh1h  = (half_t*)(ws + 4194304);          // 1536x512
    half_t* wih2h  = (half_t*)(ws + 5767168);          // 3072x512
    half_t* whh2h  = (half_t*)(ws + 8912896);          // 3072x1024
    half_t* xh     = (half_t*)(ws + 16777216);         // x fp16 [16..49.6MB)
    half_t* hrelu  = (half_t*)(ws + 16777216);         // reuses x region (x dead)
    half_t* gx1    = (half_t*)(ws + 50331648);         // [48..96MB)
    half_t* gx2    = (half_t*)(ws + 50331648);         // reuses gx1 region (gx1 dead)
    float*  out    = (float*)d_out;

    hipMemsetAsync(ws, 0, 4096, stream);               // barrier counters = 0

    k_cvt<<<16384, 256, 0, stream>>>(x,     xh,    4194304);
    k_cvt<<<1536,  256, 0, stream>>>(w_ih1, wih1h, 393216);
    k_cvt<<<768,   256, 0, stream>>>(w_hh1, whh1h, 196608);
    k_cvt<<<1536,  256, 0, stream>>>(w_ih2, wih2h, 393216);
    k_cvt<<<3072,  256, 0, stream>>>(w_hh2, whh2h, 786432);

    // gx1 = x @ w_ih1^T + b_ih1   [16384 x 1536], K=1024
    k_gemm<1024><<<dim3(12, 128), 256, 0, stream>>>(xh, wih1h, b_ih1, gx1, 1536);
    // layer-1 recurrence -> hrelu
    k_phase1<<<256, 256, 0, stream>>>(whh1h, b_hh1, gx1, hrelu, h1f16, h1f32, ctr);
    // gx2 = relu(h1) @ w_ih2^T + b_ih2   [16384 x 3072], K=512
    k_gemm<512><<<dim3(24, 128), 256, 0, stream>>>(hrelu, wih2h, b_ih2, gx2, 3072);
    // layer-2 recurrence -> out (fp32)
    k_phase2<<<256, 256, 0, stream>>>(whh2h, b_hh2, gx2, out, h2f16, h2f32, ctr + 8);
}

// Round 3
// 2139.162 us; speedup vs baseline: 3.0618x; 3.0618x over previous
//
#include <hip/hip_runtime.h>

typedef _Float16 half_t;
typedef _Float16 half8  __attribute__((ext_vector_type(8)));
typedef _Float16 half4v __attribute__((ext_vector_type(4)));
typedef float    f32x4  __attribute__((ext_vector_type(4)));
typedef int      i32x4  __attribute__((ext_vector_type(4)));

#define NB 64
#define NT 256
#define NI 1024
#define NH 512

// ---- cache-bypassing (MALL-coherent) 16B load/store + 4B slot ops ----
__device__ __forceinline__ void gload16_cc(i32x4& v, const void* p) {
    asm volatile("global_load_dwordx4 %0, %1, off sc0 sc1"
                 : "=v"(v) : "v"(p) : "memory");
}
__device__ __forceinline__ void gstore16_cc(void* p, i32x4 v) {
    asm volatile("global_store_dwordx4 %0, %1, off sc0 sc1"
                 :: "v"(p), "v"(v) : "memory");
}

// ---------------- flag-array group barrier ----------------
// slots[i] holds the generation number WG i has arrived at (monotone).
// Caller must __syncthreads() BEFORE (all producer work done / LDS stable).
// Wave 0: drain own global stores, leader stores slot, all lanes poll all
// slots with one wave-wide sc0sc1 load until every slot >= gen.
__device__ __forceinline__ void flag_barrier(unsigned* slots, int nslots,
                                             int my, unsigned gen, int tid) {
    if (tid < 64) {
        asm volatile("s_waitcnt vmcnt(0)" ::: "memory");   // h stores visible first
        if (tid == 0) {
            unsigned gv = gen;
            asm volatile("global_store_dword %0, %1, off sc0 sc1"
                         :: "v"(slots + my), "v"(gv) : "memory");
        }
        const unsigned* p = slots + (tid & (nslots - 1));
        int guard = 0;
        while (true) {
            unsigned v;
            asm volatile("global_load_dword %0, %1, off sc0 sc1"
                         : "=v"(v) : "v"(p) : "memory");
            asm volatile("s_waitcnt vmcnt(0)" ::: "memory");
            if (__all(v >= gen)) break;
            __builtin_amdgcn_s_sleep(1);
            if (++guard > (1 << 22)) break;   // failsafe: wrong beats hang
        }
    }
    __syncthreads();
}

// ---------------- fp32 -> fp16 convert ----------------
__global__ __launch_bounds__(256) void k_cvt(const float* __restrict__ s,
                                             half_t* __restrict__ d, int n4) {
    int i = blockIdx.x * 256 + threadIdx.x;
    if (i < n4) {
        float4 v = reinterpret_cast<const float4*>(s)[i];
        half4v h;
        h[0] = (half_t)v.x; h[1] = (half_t)v.y; h[2] = (half_t)v.z; h[3] = (half_t)v.w;
        reinterpret_cast<half4v*>(d)[i] = h;
    }
}

// ---------------- GEMM: C[M,N](f16) = A[M,K](f16) * Bw[N,K]^T + bias ----------------
template <int K>
__global__ __launch_bounds__(256) void k_gemm(const half_t* __restrict__ A,
                                              const half_t* __restrict__ Bw,
                                              const float* __restrict__ bias,
                                              half_t* __restrict__ C, int N) {
    constexpr int BK = 64;
    __shared__ half_t Al[2][128 * BK] __attribute__((aligned(16)));
    __shared__ half_t Bl[2][128 * BK] __attribute__((aligned(16)));

    const int tid = threadIdx.x, lane = tid & 63, wv = tid >> 6;
    const long m0 = (long)blockIdx.y * 128;
    const long n0 = (long)blockIdx.x * 128;
    const int wm = (wv >> 1) * 64, wn = (wv & 1) * 64;

    f32x4 acc[4][4];
#pragma unroll
    for (int nt = 0; nt < 4; ++nt) {
        float bv = bias[n0 + wn + nt * 16 + (lane & 15)];
#pragma unroll
        for (int mt = 0; mt < 4; ++mt) acc[mt][nt] = (f32x4){bv, bv, bv, bv};
    }

    auto stage = [&](int buf, int kt) {
#pragma unroll
        for (int j = 0; j < 4; ++j) {
            int c = tid + 256 * j;
            int row = c >> 3, cin = c & 7;
            int dst = row * BK + ((cin ^ (row & 7)) << 3);
            *reinterpret_cast<int4*>(&Al[buf][dst]) =
                *reinterpret_cast<const int4*>(A + (m0 + row) * K + kt * BK + cin * 8);
            *reinterpret_cast<int4*>(&Bl[buf][dst]) =
                *reinterpret_cast<const int4*>(Bw + (n0 + row) * K + kt * BK + cin * 8);
        }
    };

    stage(0, 0);
    __syncthreads();
    constexpr int NK = K / BK;
    int buf = 0;
    for (int kt = 0; kt < NK; ++kt) {
        if (kt + 1 < NK) stage(buf ^ 1, kt + 1);
        half8 af[4][2], bf[4][2];
#pragma unroll
        for (int mt = 0; mt < 4; ++mt)
#pragma unroll
            for (int ks = 0; ks < 2; ++ks) {
                int lr = wm + mt * 16 + (lane & 15);
                int off = lr * BK + ((ks * 32 + 8 * (lane >> 4)) ^ ((lr & 7) << 3));
                af[mt][ks] = *reinterpret_cast<const half8*>(&Al[buf][off]);
            }
#pragma unroll
        for (int nt = 0; nt < 4; ++nt)
#pragma unroll
            for (int ks = 0; ks < 2; ++ks) {
                int lr = wn + nt * 16 + (lane & 15);
                int off = lr * BK + ((ks * 32 + 8 * (lane >> 4)) ^ ((lr & 7) << 3));
                bf[nt][ks] = *reinterpret_cast<const half8*>(&Bl[buf][off]);
            }
#pragma unroll
        for (int mt = 0; mt < 4; ++mt)
#pragma unroll
            for (int nt = 0; nt < 4; ++nt)
#pragma unroll
                for (int ks = 0; ks < 2; ++ks)
                    acc[mt][nt] = __builtin_amdgcn_mfma_f32_16x16x32_f16(
                        af[mt][ks], bf[nt][ks], acc[mt][nt], 0, 0, 0);
        __syncthreads();
        buf ^= 1;
    }
#pragma unroll
    for (int mt = 0; mt < 4; ++mt)
#pragma unroll
        for (int nt = 0; nt < 4; ++nt)
#pragma unroll
            for (int i = 0; i < 4; ++i) {
                long row = m0 + wm + mt * 16 + 4 * (lane >> 4) + i;
                long col = n0 + wn + nt * 16 + (lane & 15);
                C[row * N + col] = (half_t)acc[mt][nt][i];
            }
}

// ---------------- Phase 1: layer-1 recurrence (persistent) ----------------
// 8 groups x 32 WGs; group g owns batches [8g,8g+8). WG owns 16 h-elems.
__global__ __launch_bounds__(256, 1) void k_phase1(const half_t* __restrict__ whh,
                                                   const float* __restrict__ bhh,
                                                   const half_t* __restrict__ gx,
                                                   half_t* __restrict__ hrelu,
                                                   half_t* __restrict__ hf16,
                                                   unsigned* __restrict__ slots) {
    __shared__ half_t wl[48 * NH] __attribute__((aligned(16)));   // 48KB
    __shared__ half_t hl[16 * NH] __attribute__((aligned(16)));   // 16KB
    __shared__ float xch[3][8][16];
    __shared__ half_t hstore[8][16] __attribute__((aligned(16)));

    const int tid = threadIdx.x, lane = tid & 63, wv = tid >> 6;
    const int g = blockIdx.x & 7, memb = blockIdx.x >> 3;
    const int e0 = memb * 16;
    unsigned* gslots = slots + g * 64;

    // resident weight slice: local row lr = 16*gate + e -> global row gate*512+e0+e
#pragma unroll
    for (int j = 0; j < 12; ++j) {
        int c = tid + 256 * j;                 // 3072 chunks
        int lr = c >> 6, cin = c & 63;
        int grow = (lr >> 4) * NH + e0 + (lr & 15);
        int dst = lr * NH + ((cin ^ (lr & 7)) << 3);
        *reinterpret_cast<int4*>(&wl[dst]) =
            *reinterpret_cast<const int4*>(whh + (long)grow * NH + cin * 8);
    }
    // zero A-tile pad rows 8..15 (stay zero forever)
#pragma unroll
    for (int j = 0; j < 2; ++j) {
        int c = tid + 256 * j;
        int lr = 8 + (c >> 6), cin = c & 63;
        int4 z; z.x = z.y = z.z = z.w = 0;
        *reinterpret_cast<int4*>(&hl[lr * NH + cin * 8]) = z;
    }
    // zero initial h (buffer 0) for this WG's slice — wave 0
    if (tid < 16) {
        i32x4 z = (i32x4){0, 0, 0, 0};
        int b = tid >> 1, seg = tid & 1;
        gstore16_cc(hf16 + (g * 8 + b) * NH + e0 + seg * 8, z);
    }
    float hp = 0.f;                            // register-resident h state (tid<128)
    __syncthreads();
    flag_barrier(gslots, 32, memb, 1, tid);

    const float bgate = (wv < 3) ? bhh[wv * NH + e0 + (lane & 15)] : 0.f;
    const int b = tid >> 4, e = tid & 15;

    for (int t = 0; t < NT; ++t) {
        const half_t* hsrc = hf16 + (t & 1) * (NB * NH);
        // stage current h (8 rows x 512) into swizzled LDS via sc0sc1 loads
        i32x4 sv[2];
#pragma unroll
        for (int j = 0; j < 2; ++j) {
            int c = tid + 256 * j;             // 512 chunks
            int lr = c >> 6, cin = c & 63;
            gload16_cc(sv[j], hsrc + (g * 8 + lr) * NH + cin * 8);
        }
        // hoist gx loads (normal cached loads) to overlap latency
        float xr = 0.f, xz = 0.f, xn = 0.f;
        long rowbase = 0;
        if (tid < 128) {
            rowbase = (long)(g * 8 + b) * NT + t;
            long gbase = rowbase * (3 * NH) + e0 + e;
            xr = (float)gx[gbase];
            xz = (float)gx[gbase + NH];
            xn = (float)gx[gbase + 2 * NH];
        }
        asm volatile("s_waitcnt vmcnt(0)" ::: "memory");
#pragma unroll
        for (int j = 0; j < 2; ++j) {
            int c = tid + 256 * j;
            int lr = c >> 6, cin = c & 63;
            *reinterpret_cast<i32x4*>(&hl[lr * NH + ((cin ^ (lr & 7)) << 3)]) = sv[j];
        }
        __syncthreads();

        if (wv < 3) {                          // wave wv computes gate wv
            f32x4 a0 = (f32x4){bgate, bgate, bgate, bgate};
            f32x4 a1 = (f32x4){0.f, 0.f, 0.f, 0.f};
#pragma unroll
            for (int ks = 0; ks < 16; ks += 2) {
                int ar = lane & 15;
                int br = wv * 16 + (lane & 15);
                int ao0 = ar * NH + ((ks * 32 + 8 * (lane >> 4)) ^ ((ar & 7) << 3));
                int bo0 = br * NH + ((ks * 32 + 8 * (lane >> 4)) ^ ((br & 7) << 3));
                int ao1 = ar * NH + (((ks + 1) * 32 + 8 * (lane >> 4)) ^ ((ar & 7) << 3));
                int bo1 = br * NH + (((ks + 1) * 32 + 8 * (lane >> 4)) ^ ((br & 7) << 3));
                a0 = __builtin_amdgcn_mfma_f32_16x16x32_f16(
                    *reinterpret_cast<const half8*>(&hl[ao0]),
                    *reinterpret_cast<const half8*>(&wl[bo0]), a0, 0, 0, 0);
                a1 = __builtin_amdgcn_mfma_f32_16x16x32_f16(
                    *reinterpret_cast<const half8*>(&hl[ao1]),
                    *reinterpret_cast<const half8*>(&wl[bo1]), a1, 0, 0, 0);
            }
            f32x4 acc = a0 + a1;
            if (lane < 32) {
#pragma unroll
                for (int i = 0; i < 4; ++i)
                    xch[wv][4 * (lane >> 4) + i][lane & 15] = acc[i];
            }
        }
        __syncthreads();

        if (tid < 128) {                       // gate combine, one thread per (b,e)
            float r = 1.f / (1.f + __expf(-(xr + xch[0][b][e])));
            float z = 1.f / (1.f + __expf(-(xz + xch[1][b][e])));
            float n = tanhf(xn + r * xch[2][b][e]);
            float hn = (1.f - z) * n + z * hp;
            hp = hn;
            hrelu[rowbase * NH + e0 + e] = (half_t)fmaxf(hn, 0.f);
            hstore[b][e] = (half_t)hn;
        }
        __syncthreads();

        if (t + 1 < NT) {
            if (tid < 16) {
                int bb = tid >> 1, seg = tid & 1;
                i32x4 v = *reinterpret_cast<const i32x4*>(&hstore[bb][seg * 8]);
                gstore16_cc(hf16 + ((t + 1) & 1) * (NB * NH) + (g * 8 + bb) * NH + e0 + seg * 8, v);
            }
            flag_barrier(gslots, 32, memb, t + 2, tid);
        }
    }
}

// ---------------- Phase 2: layer-2 recurrence (persistent) ----------------
// 4 groups x 64 WGs; group g owns batches [16g,16g+16). WG owns 16 out-elems.
__global__ __launch_bounds__(256, 1) void k_phase2(const half_t* __restrict__ whh,
                                                   const float* __restrict__ bhh,
                                                   const half_t* __restrict__ gx,
                                                   float* __restrict__ out,
                                                   half_t* __restrict__ hf16,
                                                   unsigned* __restrict__ slots) {
    __shared__ half_t wl[48 * NI] __attribute__((aligned(16)));   // 96KB
    __shared__ half_t hl[16 * NI] __attribute__((aligned(16)));   // 32KB
    __shared__ float xch[3][16][16];
    __shared__ half_t hstore[16][16] __attribute__((aligned(16)));

    const int tid = threadIdx.x, lane = tid & 63, wv = tid >> 6;
    const int xcd = blockIdx.x & 7;
    const int g = xcd >> 1;
    const int memb = ((blockIdx.x >> 3) << 1) | (xcd & 1);  // 0..63
    const int e0 = memb * 16;
    unsigned* gslots = slots + g * 64;

#pragma unroll
    for (int j = 0; j < 24; ++j) {
        int c = tid + 256 * j;                 // 6144 chunks
        int lr = c >> 7, cin = c & 127;
        int grow = (lr >> 4) * NI + e0 + (lr & 15);
        int dst = lr * NI + ((cin ^ (lr & 7)) << 3);
        *reinterpret_cast<int4*>(&wl[dst]) =
            *reinterpret_cast<const int4*>(whh + (long)grow * NI + cin * 8);
    }
    if (tid < 32) {
        i32x4 z = (i32x4){0, 0, 0, 0};
        int b = tid >> 1, seg = tid & 1;
        gstore16_cc(hf16 + (g * 16 + b) * NI + e0 + seg * 8, z);
    }
    float hp = 0.f;
    __syncthreads();
    flag_barrier(gslots, 64, memb, 1, tid);

    const float bgate = (wv < 3) ? bhh[wv * NI + e0 + (lane & 15)] : 0.f;
    const int b = tid >> 4, e = tid & 15;

    for (int t = 0; t < NT; ++t) {
        const half_t* hsrc = hf16 + (t & 1) * (NB * NI);
        i32x4 sv[8];
#pragma unroll
        for (int j = 0; j < 8; ++j) {
            int c = tid + 256 * j;             // 2048 chunks
            int lr = c >> 7, cin = c & 127;
            gload16_cc(sv[j], hsrc + (g * 16 + lr) * NI + cin * 8);
        }
        long rowbase = (long)(g * 16 + b) * NT + t;
        long gbase = rowbase * (3 * NI) + e0 + e;
        float xr = (float)gx[gbase];
        float xz = (float)gx[gbase + NI];
        float xn = (float)gx[gbase + 2 * NI];
        asm volatile("s_waitcnt vmcnt(0)" ::: "memory");
#pragma unroll
        for (int j = 0; j < 8; ++j) {
            int c = tid + 256 * j;
            int lr = c >> 7, cin = c & 127;
            *reinterpret_cast<i32x4*>(&hl[lr * NI + ((cin ^ (lr & 7)) << 3)]) = sv[j];
        }
        __syncthreads();

        if (wv < 3) {
            f32x4 a0 = (f32x4){bgate, bgate, bgate, bgate};
            f32x4 a1 = (f32x4){0.f, 0.f, 0.f, 0.f};
#pragma unroll
            for (int ks = 0; ks < 32; ks += 2) {
                int ar = lane & 15;
                int br = wv * 16 + (lane & 15);
                int ao0 = ar * NI + ((ks * 32 + 8 * (lane >> 4)) ^ ((ar & 7) << 3));
                int bo0 = br * NI + ((ks * 32 + 8 * (lane >> 4)) ^ ((br & 7) << 3));
                int ao1 = ar * NI + (((ks + 1) * 32 + 8 * (lane >> 4)) ^ ((ar & 7) << 3));
                int bo1 = br * NI + (((ks + 1) * 32 + 8 * (lane >> 4)) ^ ((br & 7) << 3));
                a0 = __builtin_amdgcn_mfma_f32_16x16x32_f16(
                    *reinterpret_cast<const half8*>(&hl[ao0]),
                    *reinterpret_cast<const half8*>(&wl[bo0]), a0, 0, 0, 0);
                a1 = __builtin_amdgcn_mfma_f32_16x16x32_f16(
                    *reinterpret_cast<const half8*>(&hl[ao1]),
                    *reinterpret_cast<const half8*>(&wl[bo1]), a1, 0, 0, 0);
            }
            f32x4 acc = a0 + a1;
#pragma unroll
            for (int i = 0; i < 4; ++i)
                xch[wv][4 * (lane >> 4) + i][lane & 15] = acc[i];
        }
        __syncthreads();

        {
            float r = 1.f / (1.f + __expf(-(xr + xch[0][b][e])));
            float z = 1.f / (1.f + __expf(-(xz + xch[1][b][e])));
            float n = tanhf(xn + r * xch[2][b][e]);
            float hn = (1.f - z) * n + z * hp;
            hp = hn;
            out[rowbase * NI + e0 + e] = hn;
            hstore[b][e] = (half_t)hn;
        }
        __syncthreads();

        if (t + 1 < NT) {
            if (tid < 32) {
                int bb = tid >> 1, seg = tid & 1;
                i32x4 v = *reinterpret_cast<const i32x4*>(&hstore[bb][seg * 8]);
                gstore16_cc(hf16 + ((t + 1) & 1) * (NB * NI) + (g * 16 + bb) * NI + e0 + seg * 8, v);
            }
            flag_barrier(gslots, 64, memb, t + 2, tid);
        }
    }
}

// ---------------- launcher ----------------
extern "C" void kernel_launch(void* const* d_in, const int* in_sizes, int n_in,
                              void* d_out, int out_size, void* d_ws, size_t ws_size,
                              hipStream_t stream) {
    const float* x     = (const float*)d_in[0];
    const float* w_ih1 = (const float*)d_in[1];
    const float* w_hh1 = (const float*)d_in[2];
    const float* b_ih1 = (const float*)d_in[3];
    const float* b_hh1 = (const float*)d_in[4];
    const float* w_ih2 = (const float*)d_in[5];
    const float* w_hh2 = (const float*)d_in[6];
    const float* b_ih2 = (const float*)d_in[7];
    const float* b_hh2 = (const float*)d_in[8];

    char* ws = (char*)d_ws;
    unsigned* slots1 = (unsigned*)ws;                  // 8 groups x 64 dwords = 2KB
    unsigned* slots2 = (unsigned*)(ws + 2048);         // 4 groups x 64 dwords = 1KB
    half_t* h1f16  = (half_t*)(ws + 4096);             // 2 x 64x512 fp16 ping-pong
    half_t* h2f16  = (half_t*)(ws + 266240);           // 2 x 64x1024 fp16
    half_t* wih1h  = (half_t*)(ws + 1048576);          // 1536x1024
    half_t* whh1h  = (half_t*)(ws + 4194304);          // 1536x512
    half_t* wih2h  = (half_t*)(ws + 5767168);          // 3072x512
    half_t* whh2h  = (half_t*)(ws + 8912896);          // 3072x1024
    half_t* xh     = (half_t*)(ws + 16777216);         // x fp16
    half_t* hrelu  = (half_t*)(ws + 16777216);         // reuses x region (x dead)
    half_t* gx1    = (half_t*)(ws + 50331648);
    half_t* gx2    = (half_t*)(ws + 50331648);         // reuses gx1 region (gx1 dead)
    float*  out    = (float*)d_out;

    hipMemsetAsync(ws, 0, 4096, stream);               // barrier slots = 0

    k_cvt<<<16384, 256, 0, stream>>>(x,     xh,    4194304);
    k_cvt<<<1536,  256, 0, stream>>>(w_ih1, wih1h, 393216);
    k_cvt<<<768,   256, 0, stream>>>(w_hh1, whh1h, 196608);
    k_cvt<<<1536,  256, 0, stream>>>(w_ih2, wih2h, 393216);
    k_cvt<<<3072,  256, 0, stream>>>(w_hh2, whh2h, 786432);

    // gx1 = x @ w_ih1^T + b_ih1   [16384 x 1536], K=1024
    k_gemm<1024><<<dim3(12, 128), 256, 0, stream>>>(xh, wih1h, b_ih1, gx1, 1536);
    // layer-1 recurrence -> hrelu
    k_phase1<<<256, 256, 0, stream>>>(whh1h, b_hh1, gx1, hrelu, h1f16, slots1);
    // gx2 = relu(h1) @ w_ih2^T + b_ih2   [16384 x 3072], K=512
    k_gemm<512><<<dim3(24, 128), 256, 0, stream>>>(hrelu, wih2h, b_ih2, gx2, 3072);
    // layer-2 recurrence -> out (fp32)
    k_phase2<<<256, 256, 0, stream>>>(whh2h, b_hh2, gx2, out, h2f16, slots2);
}